// Round 4
// baseline (46.948 us; speedup 1.0000x reference)
//
#include <hip/hip_runtime.h>

// KeypointPostProcessor: B=256, Q=2048, K=17, C=51 channels per row.
// out[b,q,c] for c<34: clip(pred*bw_or_bh + x1_or_y1, 0, img_dim); c>=34: pass-through.
// Everything zeroed where padding_mask[b,q].
// NOTE: harness delivers the bool padding_mask as int32 (one int per element).

namespace {

constexpr unsigned QLOG2 = 11;   // Q = 2048
constexpr unsigned CCH   = 51;   // 3*K
constexpr unsigned XYCH  = 34;   // 2*K

struct RowParams {
    float x1, y1, bw, bh, iw, ih;
    bool masked;
};

__device__ __forceinline__ RowParams row_params(
    unsigned row,
    const float4* __restrict__ boxes4,
    const int* __restrict__ mask,
    const int2* __restrict__ sizes2)
{
    RowParams rp;
    const unsigned b = row >> QLOG2;
    const int2 hw = sizes2[b];          // (h, w)
    const int h = hw.x, w = hw.y;
    const int mx = h > w ? h : w;
    const float left = (float)((mx - w) >> 1);
    const float top  = (float)((mx - h) >> 1);
    const float ms = (float)mx;
    rp.iw = (float)w;
    rp.ih = (float)h;
    const float4 bx = boxes4[row];      // (cx, cy, w, h)
    const float x1 = fminf(fmaxf((bx.x - 0.5f * bx.z) * ms - left, 0.0f), rp.iw);
    const float y1 = fminf(fmaxf((bx.y - 0.5f * bx.w) * ms - top , 0.0f), rp.ih);
    const float x2 = fminf(fmaxf((bx.x + 0.5f * bx.z) * ms - left, 0.0f), rp.iw);
    const float y2 = fminf(fmaxf((bx.y + 0.5f * bx.w) * ms - top , 0.0f), rp.ih);
    rp.x1 = x1; rp.y1 = y1;
    rp.bw = x2 - x1; rp.bh = y2 - y1;
    rp.masked = (mask[row] != 0);
    return rp;
}

} // namespace

__global__ __launch_bounds__(256) void kp_post_kernel(
    const float*  __restrict__ pred,
    const float4* __restrict__ boxes4,
    const int*    __restrict__ mask,
    const int2*   __restrict__ sizes2,
    float* __restrict__ out,
    unsigned total4)
{
    const unsigned stride = gridDim.x * blockDim.x;
    for (unsigned t = blockIdx.x * blockDim.x + threadIdx.x; t < total4; t += stride) {
        const unsigned e = t * 4u;
        unsigned row = e / CCH;          // single magic-divide by 51
        unsigned c   = e - row * CCH;
        const float4 v = reinterpret_cast<const float4*>(pred)[t];
        float in[4] = {v.x, v.y, v.z, v.w};
        RowParams rp = row_params(row, boxes4, mask, sizes2);
        float o[4];
#pragma unroll
        for (int j = 0; j < 4; ++j) {
            if (c == CCH) {              // crossed into next row
                c = 0u;
                ++row;
                rp = row_params(row, boxes4, mask, sizes2);
            }
            float r;
            if (c >= XYCH) {
                r = in[j];               // score channels pass through
            } else if ((c & 1u) == 0u) { // x coordinate
                r = fminf(fmaxf(fmaf(in[j], rp.bw, rp.x1), 0.0f), rp.iw);
            } else {                     // y coordinate
                r = fminf(fmaxf(fmaf(in[j], rp.bh, rp.y1), 0.0f), rp.ih);
            }
            o[j] = rp.masked ? 0.0f : r;
            ++c;
        }
        reinterpret_cast<float4*>(out)[t] = make_float4(o[0], o[1], o[2], o[3]);
    }
}

extern "C" void kernel_launch(void* const* d_in, const int* in_sizes, int n_in,
                              void* d_out, int out_size, void* d_ws, size_t ws_size,
                              hipStream_t stream) {
    const float*  pred   = (const float*)d_in[0];
    const float4* boxes4 = (const float4*)d_in[1];
    const int*    mask   = (const int*)d_in[2];
    const int2*   sizes2 = (const int2*)d_in[3];
    float* out = (float*)d_out;

    const unsigned total  = (unsigned)out_size;   // 256*2048*51 = 26,738,688 (div by 4)
    const unsigned total4 = total / 4u;

    const int block = 256;
    unsigned need = (total4 + block - 1) / block;
    int grid = (need < 2048u) ? (int)need : 2048;

    hipLaunchKernelGGL(kp_post_kernel, dim3(grid), dim3(block), 0, stream,
                       pred, boxes4, mask, sizes2, out, total4);
}